// Round 12
// baseline (144.662 us; speedup 1.0000x reference)
//
#include <hip/hip_runtime.h>
#include <stdint.h>

// ---------------------------------------------------------------------------
// LinearBlock: out[b, p*8+o] = clip((sum_{q,i} Wq[p,q,o,i]*xq[b,q*8+i])^2, 0, 6)
// Exact int8 path (11x verified):
//   xq = xu/255, wq = wi*2/127, dot=(sum xu*wi)*2/(255*127); zero-point via
//   xs=xu-128 and +128*rowsum[n].
//
// Round 12: NO LDS, NO BARRIERS in the GEMM. Both quant passes write
// k-chunk-major transposes (xqT[kc][b], wqT[kc][col]; 16 K-bytes per chunk)
// so every MFMA fragment is a per-lane-coalesced global_load_dwordx4 straight
// from L2 into registers. Each wave streams 24 loads + 32 MFMAs per K-tile
// with no block-wide sync -- waves drift, compiler pipelines freely.
// Rationale: 10 schedule variants all pinned at ~30% MfmaUtil; r8 probe
// proved MFMA+barriers alone run at ceiling; no pipe is throughput-bound ->
// the barrier-staged LDS consumption structure itself was the cap.
// ---------------------------------------------------------------------------

typedef int i32x4  __attribute__((ext_vector_type(4)));
typedef int i32x16 __attribute__((ext_vector_type(16)));

#define B_DIM   16384
#define IN_DIM  2048
#define OUT_DIM 2048

#define BM 256
#define BN 256
#define BK 128
#define KTILES (IN_DIM / BK)           // 16
#define AKC ((size_t)B_DIM * 16)       // 262144 B per A k-chunk slab
#define BKC ((size_t)OUT_DIM * 16)     // 32768 B per B k-chunk slab

__device__ __forceinline__ int q4(float4 v) {
    int a = (int)rintf(fminf(fmaxf(v.x, 0.f), 1.f) * 255.f) - 128;
    int b = (int)rintf(fminf(fmaxf(v.y, 0.f), 1.f) * 255.f) - 128;
    int c = (int)rintf(fminf(fmaxf(v.z, 0.f), 1.f) * 255.f) - 128;
    int d = (int)rintf(fminf(fmaxf(v.w, 0.f), 1.f) * 255.f) - 128;
    return (a & 255) | ((b & 255) << 8) | ((c & 255) << 16) | ((d & 255) << 24);
}

// --- quantize x -> TRANSPOSED xqT: byte(kc,b,j) = xq[b][kc*16+j] ----------
// Block: 64 b-rows x 256 k (16 kc). LDS transpose; coalesced in and out.
__global__ __launch_bounds__(256) void quant_x_kernel(const float* __restrict__ x,
                                                      int8_t* __restrict__ xqT) {
    __shared__ int8_t sm[64 * 272];   // 16 B pad per 256-B row
    int bid = blockIdx.x;
    int b0 = (bid >> 3) * 64;
    int kc0 = (bid & 7) * 16;
    int t = threadIdx.x;

    int rl = t >> 2;                  // 0..63
    const float* xr = x + (size_t)(b0 + rl) * IN_DIM + (size_t)kc0 * 16 + (t & 3) * 16;
#pragma unroll
    for (int s = 0; s < 4; ++s) {
        const float4* p = (const float4*)(xr + s * 64);
        i32x4 pk;
        pk[0] = q4(p[0]); pk[1] = q4(p[1]); pk[2] = q4(p[2]); pk[3] = q4(p[3]);
        *(i32x4*)(sm + rl * 272 + ((t & 3) + 4 * s) * 16) = pk;
    }
    __syncthreads();

    int bl = t & 63, w = t >> 6;
#pragma unroll
    for (int s = 0; s < 4; ++s) {
        int kcl = s * 4 + w;          // 0..15
        i32x4 v = *(const i32x4*)(sm + bl * 272 + kcl * 16);
        *(i32x4*)(xqT + (size_t)(kc0 + kcl) * AKC + (size_t)(b0 + bl) * 16) = v;
    }
}

// --- quantize weight -> TRANSPOSED wqT (r11-verified) + rowsum ------------
__global__ __launch_bounds__(256) void quant_w_kernel(const float* __restrict__ w,
                                                      int8_t* __restrict__ wqT,
                                                      int* __restrict__ rowsum) {
    int p = blockIdx.x;
    int t = threadIdx.x;
    const float* wp = w + (size_t)p * 16384;
    int lsum = 0;
    int n = p * 8 + (t & 7);
#pragma unroll
    for (int s = 0; s < 8; ++s) {
        int g = t + s * 256;
        float4 v0 = *(const float4*)(wp + g * 8);
        float4 v1 = *(const float4*)(wp + g * 8 + 4);
        float f[8] = {v0.x, v0.y, v0.z, v0.w, v1.x, v1.y, v1.z, v1.w};
        union { int8_t c[8]; long long ll; } u;
#pragma unroll
        for (int e = 0; e < 8; ++e) {
            float c = fminf(fmaxf(f[e], -2.0f), 2.0f);
            int q = (int)rintf(c * 63.5f);
            u.c[e] = (int8_t)q;
            lsum += q;
        }
        *(long long*)(wqT + ((size_t)(g >> 4) << 15) + n * 16 + ((g >> 3) & 1) * 8) = u.ll;
    }
    atomicAdd(&rowsum[n], lsum);
}

#define LD(p) (*(const i32x4*)(p))
#define MFMA32(a, b, c) __builtin_amdgcn_mfma_i32_32x32x32_i8(a, b, c, 0, 0, 0)

// --- int8 GEMM: 256x256, 8 waves, NO LDS / NO BARRIERS, L2->reg stream ---
__global__ __launch_bounds__(512, 2) void gemm_i8_kernel(const int8_t* __restrict__ AT,
                                                         const int8_t* __restrict__ WT,
                                                         const int* __restrict__ rowsum,
                                                         float* __restrict__ out) {
    // XCD-aware swizzle: 512 wgs, 8 XCDs; per XCD: 8 consecutive blocks share
    // one A panel (tm), B cycles all tn -> A panel + B slab hot in L2.
    int bid = blockIdx.x;
    int wg = (bid & 7) * 64 + (bid >> 3);
    int tm = wg >> 3;
    int tn = wg & 7;
    int browG = tm * BM;
    int bcolG = tn * BN;

    int tid  = threadIdx.x;
    int lane = tid & 63;
    int wv   = tid >> 6;
    int wr = wv >> 2, wc = wv & 3;    // 2x4 waves, wave tile 128x64
    int l31 = lane & 31;
    int hi  = lane >> 5;              // 0..1

    // A frag (m, ks, kt): lane l31 reads xqT[kt*8+2*ks+hi][browG+wr*128+m*32+l31]
    // -> lanes = consecutive 16B chunks = coalesced. Same for B (r11-verified).
    const int8_t* gAT = AT + (size_t)hi * AKC + ((size_t)(browG + wr * 128 + l31) << 4);
    const int8_t* gBT = WT + (size_t)hi * BKC + ((size_t)(bcolG + wc * 64 + l31) << 4);

    i32x16 acc[4][2];
#pragma unroll
    for (int m = 0; m < 4; ++m)
#pragma unroll
        for (int n = 0; n < 2; ++n)
            acc[m][n] = (i32x16){0, 0, 0, 0, 0, 0, 0, 0, 0, 0, 0, 0, 0, 0, 0, 0};

#pragma unroll 1
    for (int kt = 0; kt < KTILES; ++kt) {
        const int8_t* pa = gAT + (size_t)kt * (8 * AKC);
        const int8_t* pb = gBT + (size_t)kt * (8 * BKC);
#pragma unroll
        for (int ks = 0; ks < 4; ++ks) {
            const int8_t* qa = pa + (size_t)ks * (2 * AKC);
            const int8_t* qb = pb + (size_t)ks * (2 * BKC);
            i32x4 a0 = LD(qa);
            i32x4 a1 = LD(qa + 512);
            i32x4 a2 = LD(qa + 1024);
            i32x4 a3 = LD(qa + 1536);
            i32x4 b0 = LD(qb);
            i32x4 b1 = LD(qb + 512);
            acc[0][0] = MFMA32(a0, b0, acc[0][0]);
            acc[0][1] = MFMA32(a0, b1, acc[0][1]);
            acc[1][0] = MFMA32(a1, b0, acc[1][0]);
            acc[1][1] = MFMA32(a1, b1, acc[1][1]);
            acc[2][0] = MFMA32(a2, b0, acc[2][0]);
            acc[2][1] = MFMA32(a2, b1, acc[2][1]);
            acc[3][0] = MFMA32(a3, b0, acc[3][0]);
            acc[3][1] = MFMA32(a3, b1, acc[3][1]);
        }
    }

    // ---- epilogue: zero-point, scale, photodetect square, ReLUN(6) ----
    // C/D 32x32 map: col = lane&31, row = (reg&3) + 8*(reg>>2) + 4*(lane>>5)
    const float scale = (float)(2.0 / 32385.0);
#pragma unroll
    for (int n = 0; n < 2; ++n) {
        int col = bcolG + wc * 64 + n * 32 + l31;
        int rs128 = rowsum[col] << 7;
#pragma unroll
        for (int m = 0; m < 4; ++m) {
            int rb = browG + wr * 128 + m * 32 + hi * 4;
#pragma unroll
            for (int r = 0; r < 16; ++r) {
                int row = rb + (r & 3) + 8 * (r >> 2);
                float f = (float)(acc[m][n][r] + rs128) * scale;
                f = f * f;
                f = fminf(f, 6.0f);
                out[(size_t)row * OUT_DIM + col] = f;
            }
        }
    }
}

extern "C" void kernel_launch(void* const* d_in, const int* in_sizes, int n_in,
                              void* d_out, int out_size, void* d_ws, size_t ws_size,
                              hipStream_t stream) {
    const float* x  = (const float*)d_in[0];   // [16384, 2048] f32
    const float* wt = (const float*)d_in[1];   // [256, 256, 8, 8] f32
    float* out = (float*)d_out;                // [16384, 2048] f32

    char* ws = (char*)d_ws;
    int8_t* xqT = (int8_t*)ws;                                  // 32 MB
    int8_t* wqT = (int8_t*)(ws + (size_t)B_DIM * IN_DIM);      // 4 MB
    int*    rowsum = (int*)(ws + (size_t)B_DIM * IN_DIM
                               + (size_t)OUT_DIM * IN_DIM);     // 8 KB

    hipMemsetAsync(rowsum, 0, OUT_DIM * sizeof(int), stream);
    quant_x_kernel<<<(B_DIM / 64) * (IN_DIM / 256), 256, 0, stream>>>(x, xqT);
    quant_w_kernel<<<256, 256, 0, stream>>>(wt, wqT, rowsum);
    gemm_i8_kernel<<<(B_DIM / BM) * (OUT_DIM / BN), 512, 0, stream>>>(xqT, wqT, rowsum, out);
}

// Round 13
// 111.097 us; speedup vs baseline: 1.3021x; 1.3021x over previous
//
#include <hip/hip_runtime.h>
#include <stdint.h>

// ---------------------------------------------------------------------------
// LinearBlock: out[b, p*8+o] = clip((sum_{q,i} Wq[p,q,o,i]*xq[b,q*8+i])^2, 0, 6)
// Exact int8 path (12x verified):
//   xq = xu/255,        xu = round(clip(x,0,1)*255)       in [0,255]
//   wq = wi*2/127,      wi = round(clip(w,-2,2)*63.5)     in [-127,127]
//   dot = (sum xu*wi) * 2/(255*127);  A zero-point: xs=xu-128, +128*rowsum[n].
//
// Round 13 (final): best-measured configuration (round 7: 256x256, BK=128,
// 8 waves, dbuf, 4-phase quadrant schedule with counted vmcnt(4), both-sides
// XOR swizzle, XCD block swizzle -- GEMM ~95us, total 117.3us) plus one
// micro-fix: quant_w computes rowsum via in-block LDS reduction (block p
// owns all K for its 8 rows), removing global atomics + the memset dispatch.
//
// Structural constraint (12-round ablation): the GEMM is operand-movement
// bound; best-known plain-HIP schedule class (m201 8-phase, 1563 TF bf16)
// equals ~88us for this shape, and our i8 at ~95us is within ~8% of that
// bf16-equivalent -- i8's 2x MFMA rate is unexploitable because the per-tile
// staging/ds_read/sync critical path is byte-identical to bf16. quant_x is
// at its HBM floor (27us vs 26.6 computed). Composition floor ~115-120us.
// ---------------------------------------------------------------------------

typedef int i32x4 __attribute__((ext_vector_type(4)));

#define B_DIM   16384
#define IN_DIM  2048
#define OUT_DIM 2048

#define BM 256
#define BN 256
#define BK 128
#define KTILES (IN_DIM / BK)   // 16
#define HALF   16384           // bytes per half-tile (128 rows x 128 B)
#define BUFB   (4 * HALF)      // 64 KB: [Aa][Ab][Ba][Bb]

__device__ __forceinline__ void async16(const void* g, void* l) {
    __builtin_amdgcn_global_load_lds(
        (const __attribute__((address_space(1))) void*)g,
        (__attribute__((address_space(3))) void*)l, 16, 0, 0);
}

// --- quantize x: float [B,IN] -> int8 (value-128) [B,IN], 16 elems/thread ---
__global__ __launch_bounds__(256) void quant_x_kernel(const float* __restrict__ x,
                                                      int8_t* __restrict__ xq) {
    int i = blockIdx.x * 256 + threadIdx.x;           // 16-elem chunk id
    const float4* xv = (const float4*)x + (size_t)i * 4;
    union { int8_t c[16]; i32x4 v; } u;
#pragma unroll
    for (int j = 0; j < 4; ++j) {
        float4 v = xv[j];
        float f[4] = {v.x, v.y, v.z, v.w};
#pragma unroll
        for (int e = 0; e < 4; ++e) {
            float c = fminf(fmaxf(f[e], 0.0f), 1.0f);
            int q = (int)rintf(c * 255.0f) - 128;
            u.c[j * 4 + e] = (int8_t)q;
        }
    }
    *((i32x4*)xq + i) = u.v;
}

// --- quantize + relayout weight: [P=256,Q=256,8,8] f32 -> [2048][2048] int8
//     rowsum via in-block LDS reduction (block p owns all K of rows p*8..+7).
__global__ __launch_bounds__(256) void quant_w_kernel(const float* __restrict__ w,
                                                      int8_t* __restrict__ wq,
                                                      int* __restrict__ rowsum) {
    __shared__ int smsum[256];
    int p = blockIdx.x;          // 0..255
    int t = threadIdx.x;         // 0..255
    const float* wp = w + (size_t)p * 16384;
    int n = p * 8 + (t & 7);
    int lsum = 0;
#pragma unroll
    for (int s = 0; s < 8; ++s) {
        int g = t + s * 256;                     // 8-elem group id, 0..2047
        float4 v0 = *(const float4*)(wp + g * 8);
        float4 v1 = *(const float4*)(wp + g * 8 + 4);
        float f[8] = {v0.x, v0.y, v0.z, v0.w, v1.x, v1.y, v1.z, v1.w};
        union { int8_t c[8]; long long ll; } u;
#pragma unroll
        for (int e = 0; e < 8; ++e) {
            float c = fminf(fmaxf(f[e], -2.0f), 2.0f);
            int q = (int)rintf(c * 63.5f);       // == round((w/2)*127), exact
            u.c[e] = (int8_t)q;
            lsum += q;
        }
        int kg = g >> 3;
        *(long long*)(wq + (size_t)n * 2048 + kg * 8) = u.ll;
    }
    smsum[t] = lsum;
    __syncthreads();
    if (t < 8) {
        int s = 0;
#pragma unroll
        for (int j = 0; j < 32; ++j) s += smsum[t + j * 8];
        rowsum[p * 8 + t] = s;
    }
}

#define SB0 __builtin_amdgcn_sched_barrier(0)
#define BAR __builtin_amdgcn_s_barrier()
#define WLG0 asm volatile("s_waitcnt lgkmcnt(0)" ::: "memory")
#define WVM(n) asm volatile("s_waitcnt vmcnt(" #n ")" ::: "memory")
#define LD(p) (*(const i32x4*)(p))

// 16 MFMA quadrant: acc[MH][NH] over mf(4) x nf(2) x kk(2)
#define CLPH(MH, NH, BF)                                                      \
    _Pragma("unroll")                                                         \
    for (int mf = 0; mf < 4; ++mf)                                            \
        _Pragma("unroll")                                                     \
        for (int nf = 0; nf < 2; ++nf)                                        \
            _Pragma("unroll")                                                 \
            for (int kk = 0; kk < 2; ++kk)                                    \
                acc[MH][NH][mf][nf] = __builtin_amdgcn_mfma_i32_16x16x64_i8(  \
                    af[2 * mf + kk], BF[2 * nf + kk], acc[MH][NH][mf][nf], 0, 0, 0);

#define RD_A(BASEOFF)                                                         \
    af[0] = LD(base + (BASEOFF) + aoff0);                                     \
    af[1] = LD(base + (BASEOFF) + (aoff0 ^ 64));                              \
    af[2] = LD(base + (BASEOFF) + aoff0 + 2048);                              \
    af[3] = LD(base + (BASEOFF) + ((aoff0 + 2048) ^ 64));                     \
    af[4] = LD(base + (BASEOFF) + aoff0 + 4096);                              \
    af[5] = LD(base + (BASEOFF) + ((aoff0 + 4096) ^ 64));                     \
    af[6] = LD(base + (BASEOFF) + aoff0 + 6144);                              \
    af[7] = LD(base + (BASEOFF) + ((aoff0 + 6144) ^ 64));

#define RD_B(BF, BASEOFF)                                                     \
    BF[0] = LD(base + (BASEOFF) + boff0);                                     \
    BF[1] = LD(base + (BASEOFF) + (boff0 ^ 64));                              \
    BF[2] = LD(base + (BASEOFF) + boff0 + 2048);                              \
    BF[3] = LD(base + (BASEOFF) + ((boff0 + 2048) ^ 64));

// One K-tile on buffer BB; when STG, stages tile KT2's halves (order
// Aa,Ba,Bb,Ab) into buffer BB^1. Waits: P0 vmcnt(4); P1 vmcnt(W1);
// P2 vmcnt(W2); P3 none. Steady (W1,W2)=(4,4); tail tile (2,0).
#define DO_TILE(BB, KT2, STG, W1, W2) do {                                    \
    const int8_t* base = lds + (BB) * BUFB;                                   \
    int8_t* dst = lds + ((BB) ^ 1) * BUFB;                                    \
    const int kb = (KT2) * BK;                                                \
    /* ---- P0: quad (mh0,nh0); reads Aa(8)+Ba(4); stage Aa' ---- */          \
    WVM(4); SB0; BAR;                                                         \
    RD_A(0)                                                                   \
    RD_B(bf0, 2 * HALF)                                                       \
    if (STG) { async16(gAa + kb, dst + t16);                                  \
               async16(gAa + 131072 + kb, dst + 8192 + t16); }                \
    SB0; WLG0; SB0;                                                           \
    __builtin_amdgcn_s_setprio(1);                                            \
    CLPH(0, 0, bf0)                                                           \
    __builtin_amdgcn_s_setprio(0); SB0;                                       \
    /* ---- P1: quad (mh0,nh1); reads Bb(4); stage Ba' ---- */                \
    WVM(W1); SB0; BAR;                                                        \
    RD_B(bf1, 3 * HALF)                                                       \
    if (STG) { async16(gBa + kb, dst + 2 * HALF + t16);                       \
               async16(gBa + 131072 + kb, dst + 2 * HALF + 8192 + t16); }     \
    SB0; WLG0; SB0;                                                           \
    __builtin_amdgcn_s_setprio(1);                                            \
    CLPH(0, 1, bf1)                                                           \
    __builtin_amdgcn_s_setprio(0); SB0;                                       \
    /* ---- P2: quad (mh1,nh1); reads Ab(8); stage Bb' ---- */                \
    WVM(W2); SB0; BAR;                                                        \
    RD_A(HALF)                                                                \
    if (STG) { async16(gBb + kb, dst + 3 * HALF + t16);                       \
               async16(gBb + 131072 + kb, dst + 3 * HALF + 8192 + t16); }     \
    SB0; WLG0; SB0;                                                           \
    __builtin_amdgcn_s_setprio(1);                                            \
    CLPH(1, 1, bf1)                                                           \
    __builtin_amdgcn_s_setprio(0); SB0;                                       \
    /* ---- P3: quad (mh1,nh0); no reads; stage Ab' ---- */                   \
    BAR;                                                                      \
    if (STG) { async16(gAb + kb, dst + HALF + t16);                           \
               async16(gAb + 131072 + kb, dst + HALF + 8192 + t16); }         \
    SB0;                                                                      \
    __builtin_amdgcn_s_setprio(1);                                            \
    CLPH(1, 0, bf0)                                                           \
    __builtin_amdgcn_s_setprio(0); SB0;                                       \
} while (0)

// --- int8 GEMM: 256x256, BK=128, 8 waves, dbuf, counted-vmcnt 4-phase ---
__global__ __launch_bounds__(512, 2) void gemm_i8_kernel(const int8_t* __restrict__ A,
                                                         const int8_t* __restrict__ W,
                                                         const int* __restrict__ rowsum,
                                                         float* __restrict__ out) {
    extern __shared__ int8_t lds[];   // 2 * 64 KB

    // XCD-aware swizzle: 512 wgs, 8 XCDs, 64 contiguous tiles per XCD
    int bid = blockIdx.x;
    int wg = (bid & 7) * 64 + (bid >> 3);
    int tm = wg >> 3;                 // 64 row tiles
    int tn = wg & 7;                  // 8 col tiles
    int brow = tm * BM;
    int bcol = tn * BN;

    int tid  = threadIdx.x;
    int lane = tid & 63;
    int wv   = tid >> 6;
    int wr = wv >> 2, wc = wv & 3;    // 2x4 waves
    int l15 = lane & 15;
    int kg  = lane >> 4;              // 0..3

    // staging: per half (128 rows x 8 chunks), thread t covers rows t>>3 and
    // 64+(t>>3), chunk col t&7, swizzled: LDS (rl,c) holds global
    // (rl, c ^ ((rl>>1)&7)); ((rl>>1)&7) == (t>>4)&7 for both slices.
    int csw = (tid & 7) ^ ((tid >> 4) & 7);
    const int8_t* gAa = A + (size_t)(brow + (tid >> 3)) * IN_DIM + csw * 16;
    const int8_t* gAb = gAa + 128 * IN_DIM;
    const int8_t* gBa = W + (size_t)(bcol + (tid >> 3)) * IN_DIM + csw * 16;
    const int8_t* gBb = gBa + 128 * IN_DIM;
    const int t16 = tid * 16;

    // reads: A half-local row rl = wr*64 + mf*16 + l15; B rl = wc*32+nf*16+l15;
    // chunk kc = kk*4+kg, swizzled kc^((rl>>1)&7), (rl>>1)&7 == (l15>>1)&7.
    const int xsw   = (l15 >> 1) & 7;
    const int koff0 = ((kg ^ xsw) << 4);          // kk=0; kk=1 is ^64
    const int aoff0 = (wr * 64 + l15) * BK + koff0;   // + mf*2048
    const int boff0 = (wc * 32 + l15) * BK + koff0;   // + nf*2048

    i32x4 acc[2][2][4][2];
#pragma unroll
    for (int mh = 0; mh < 2; ++mh)
#pragma unroll
        for (int nh = 0; nh < 2; ++nh)
#pragma unroll
            for (int mf = 0; mf < 4; ++mf)
#pragma unroll
                for (int nf = 0; nf < 2; ++nf)
                    acc[mh][nh][mf][nf] = (i32x4){0, 0, 0, 0};
    i32x4 af[8], bf0[4], bf1[4];

    // ---- prologue: stage tile 0's halves in ledger order Aa,Ba,Bb,Ab ----
    async16(gAa, lds + t16);
    async16(gAa + 131072, lds + 8192 + t16);
    async16(gBa, lds + 2 * HALF + t16);
    async16(gBa + 131072, lds + 2 * HALF + 8192 + t16);
    async16(gBb, lds + 3 * HALF + t16);
    async16(gBb + 131072, lds + 3 * HALF + 8192 + t16);
    async16(gAb, lds + HALF + t16);
    async16(gAb + 131072, lds + HALF + 8192 + t16);

    // ---- main loop: 16 K-tiles, tile T (buf T&1) stages T+1 ----
#pragma unroll 1
    for (int i = 0; i < 7; ++i) {
        DO_TILE(0, 2 * i + 1, 1, 4, 4);
        DO_TILE(1, 2 * i + 2, 1, 4, 4);
    }
    DO_TILE(0, 15, 1, 4, 4);
    DO_TILE(1, 0, 0, 2, 0);   // tail: counted 2, then drain 0 (last tile only)

    // ---- epilogue: zero-point, scale, photodetect square, ReLUN(6) ----
    const float scale = (float)(2.0 / 32385.0);   // 2/(255*127)
#pragma unroll
    for (int nh = 0; nh < 2; ++nh)
#pragma unroll
        for (int nf = 0; nf < 2; ++nf) {
            int col = bcol + nh * 128 + wc * 32 + nf * 16 + l15;
            int rs128 = rowsum[col] << 7;         // 128 * sum_k wi[col,k]
#pragma unroll
            for (int mh = 0; mh < 2; ++mh)
#pragma unroll
                for (int mf = 0; mf < 4; ++mf) {
                    int row0 = brow + mh * 128 + wr * 64 + mf * 16 + kg * 4;
#pragma unroll
                    for (int r = 0; r < 4; ++r) {
                        float f = (float)(acc[mh][nh][mf][nf][r] + rs128) * scale;
                        f = f * f;
                        f = fminf(f, 6.0f);
                        out[(size_t)(row0 + r) * OUT_DIM + col] = f;
                    }
                }
        }
}

extern "C" void kernel_launch(void* const* d_in, const int* in_sizes, int n_in,
                              void* d_out, int out_size, void* d_ws, size_t ws_size,
                              hipStream_t stream) {
    const float* x  = (const float*)d_in[0];   // [16384, 2048] f32
    const float* wt = (const float*)d_in[1];   // [256, 256, 8, 8] f32
    float* out = (float*)d_out;                // [16384, 2048] f32

    char* ws = (char*)d_ws;
    int8_t* xq = (int8_t*)ws;                                   // 32 MB
    int8_t* wq = (int8_t*)(ws + (size_t)B_DIM * IN_DIM);        // 4 MB
    int*    rowsum = (int*)(ws + (size_t)B_DIM * IN_DIM
                               + (size_t)OUT_DIM * IN_DIM);     // 8 KB

    quant_x_kernel<<<(B_DIM * IN_DIM / 16) / 256, 256, 0, stream>>>(x, xq);
    quant_w_kernel<<<256, 256, 0, stream>>>(wt, wq, rowsum);
    gemm_i8_kernel<<<(B_DIM / BM) * (OUT_DIM / BN), 512, 2 * BUFB, stream>>>(xq, wq, rowsum, out);
}